// Round 7
// baseline (883.754 us; speedup 1.0000x reference)
//
#include <hip/hip_runtime.h>
#include <hip/hip_bf16.h>

#define NN 4096
#define NI 16384   // N*I
#define HH 32
#define ZLEN (HH * NN)   // shorts per zT buffer

typedef __attribute__((ext_vector_type(8))) short short8;
typedef __attribute__((ext_vector_type(4))) float f32x4;

__device__ __forceinline__ short f2bs(float f) {
  __hip_bfloat16 b = __float2bfloat16(f);
  return *(short*)&b;
}

// ---- adj f32 -> bf16, permuted into MFMA A-fragment order ----
__global__ __launch_bounds__(512) void k_cvt(const float* __restrict__ a,
                                             short* __restrict__ ab) {
  const int tid = threadIdx.x;
  const int W = tid >> 6, lane = tid & 63;
  const int fr = lane & 15, oct = lane >> 4;
  const int R = blockIdx.x;
  const float* srow = a + (long)(R * 16 + fr) * NN + W * 512 + oct * 8;
  short* drow = ab + ((long)(R * 8 + W) * 16) * 512 + lane * 8;
#pragma unroll 4
  for (int i = 0; i < 16; ++i) {
    const float4 u0 = *(const float4*)(srow + i * 32);
    const float4 u1 = *(const float4*)(srow + i * 32 + 4);
    short8 r;
    r[0] = f2bs(u0.x); r[1] = f2bs(u0.y); r[2] = f2bs(u0.z); r[3] = f2bs(u0.w);
    r[4] = f2bs(u1.x); r[5] = f2bs(u1.y); r[6] = f2bs(u1.z); r[7] = f2bs(u1.w);
    *(short8*)(drow + i * 512) = r;
  }
}

// zT B-fragment layout: element z[n][h] at short index
//   ((hb*128 + kb)*64 + hl + 16*oct)*8 + j  (hb=h>>4, hl=h&15, kb=n>>5, oct=(n>>3)&3, j=n&7)
__device__ __forceinline__ long zt_idx(int n, int h) {
  const int hb = h >> 4, hl = h & 15;
  const int kb = n >> 5, oct = (n >> 3) & 3, j = n & 7;
  return ((long)(hb * 128 + kb) * 64 + hl + 16 * oct) * 8 + j;
}

// ---------------- spline + barrier zeroing ----------------
__global__ void k_spline(const float* __restrict__ x,
                         float* __restrict__ dx0, float* __restrict__ dxh,
                         float* __restrict__ dx1, unsigned* __restrict__ bar) {
  if (blockIdx.x == 0)
    for (int i = threadIdx.x; i < 16384; i += 256) bar[i] = 0u;
  const int c = blockIdx.x * 256 + threadIdx.x;
  float y[16];
#pragma unroll
  for (int t = 0; t < 16; ++t) y[t] = x[t * NI + c];
  float cp[15], dp[15], M[16];
  cp[1] = 0.25f;
  dp[1] = (6.f * (y[2] - 2.f * y[1] + y[0])) * 0.25f;
#pragma unroll
  for (int i = 2; i <= 14; ++i) {
    float ri = 6.f * (y[i + 1] - 2.f * y[i] + y[i - 1]);
    float inv = 1.f / (4.f - cp[i - 1]);
    cp[i] = inv;
    dp[i] = (ri - dp[i - 1]) * inv;
  }
  M[0] = 0.f; M[15] = 0.f;
  M[14] = dp[14];
#pragma unroll
  for (int i = 13; i >= 1; --i) M[i] = dp[i] - cp[i] * M[i + 1];
#pragma unroll
  for (int i = 0; i < 15; ++i) {
    float b = (y[i + 1] - y[i]) - (2.f * M[i] + M[i + 1]) * (1.f / 6.f);
    float cc = 0.5f * M[i];
    float dd = (M[i + 1] - M[i]) * (1.f / 6.f);
    dx0[i * NI + c] = b;
    dxh[i * NI + c] = b + cc + 0.75f * dd;
    dx1[i * NI + c] = b + 2.f * cc + 3.f * dd;
  }
}

struct OdeP {
  const float *x, *We, *be;
  const short *adjb;
  const float *Wg, *bg, *Wt, *bt, *Wp, *bp, *Wd1, *bd1, *Wd2, *bd2;
  const float *dx0, *dxh, *dx1;
  short *ztr;        // ring: 61 buffers of ZLEN shorts, never reused
  unsigned *bar;     // [s*128 + stripe*16] arrival; flg at bar + 8192: [s*16]
  float *out;
};

// Barrier s: __syncthreads' implicit vmcnt(0) drains the agent-scope zT stores
// (acked at L3) before tid0 arrives -> no fences needed anywhere.
__device__ __forceinline__ void gbar2(const OdeP& p, int s, int bid, int tid) {
  __syncthreads();
  if (tid == 0) {
    unsigned* stri = p.bar + s * 128;
    unsigned* flg = p.bar + 8192 + s * 16;
    __hip_atomic_fetch_add(&stri[(bid & 7) * 16], 1u,
                           __ATOMIC_RELAXED, __HIP_MEMORY_SCOPE_AGENT);
    if (bid == 0) {
#pragma unroll 1
      for (int x2 = 0; x2 < 8; ++x2)
        while (__hip_atomic_load(&stri[x2 * 16], __ATOMIC_RELAXED,
                                 __HIP_MEMORY_SCOPE_AGENT) < 32u)
          __builtin_amdgcn_s_sleep(2);
      __hip_atomic_store(flg, 1u, __ATOMIC_RELAXED, __HIP_MEMORY_SCOPE_AGENT);
    } else {
      while (__hip_atomic_load(flg, __ATOMIC_RELAXED,
                               __HIP_MEMORY_SCOPE_AGENT) == 0u)
        __builtin_amdgcn_s_sleep(2);
    }
  }
  __syncthreads();
}

// ---------------- persistent ODE kernel: 256 blocks x 1024 threads ----------------
__global__ __launch_bounds__(1024) void k_ode(OdeP p) {
  __shared__ float red2[16][32][17];   // MFMA partials [row][col][wave]
  __shared__ float zn_s[16][33];
  __shared__ float h_s[16][33];
  __shared__ float ze_s[16][33];
  __shared__ float znt[16][33];        // freshly updated z tile (f32)
  __shared__ float Wg_s[32][32];
  __shared__ float Wt_s[32][32];
  __shared__ float Wp_s[32][136];
  __shared__ float Wd1_s[32][16];
  __shared__ float bgt_s[32];
  __shared__ float bp_s[128];
  __shared__ float dsm[33];            // b_d1[0:16], W_d2[16:32], b_d2[32]

  const int tid = threadIdx.x;
  const int lane = tid & 63;
  const int w = tid >> 6;              // wave 0..15
  const int bid = blockIdx.x;
  const int r0 = bid * 16;
  const int lane8 = lane * 8;
  const int r = (tid >> 5) & 15, c = tid & 31;   // epilogue coords (tid<512)

  // ---- stage constants ----
  if (tid < 1024) {
    Wg_s[tid >> 5][tid & 31] = p.Wg[tid];
    Wt_s[tid >> 5][tid & 31] = p.Wt[tid];
  }
  for (int idx = tid; idx < 4096; idx += 1024)
    Wp_s[idx >> 7][idx & 127] = p.Wp[idx];
  if (tid < 512) Wd1_s[tid >> 4][tid & 15] = p.Wd1[tid];
  if (tid < 32) bgt_s[tid] = p.bg[tid] + p.bt[tid];
  if (tid < 128) bp_s[tid] = p.bp[tid];
  if (tid < 16) { dsm[tid] = p.bd1[tid]; dsm[16 + tid] = p.Wd2[tid]; }
  if (tid == 0) dsm[32] = p.bd2[0];

  // ---- encoder: z0 for own 16 rows ----
  float zb = 0.f, k1r = 0.f, k2r = 0.f, k3r = 0.f;
  if (tid < 512) {
    const int n = r0 + r;
    const float4 xv = *(const float4*)&p.x[n * 4];
    float z0 = p.be[c];
    z0 = fmaf(xv.x, p.We[c], z0);
    z0 = fmaf(xv.y, p.We[32 + c], z0);
    z0 = fmaf(xv.z, p.We[64 + c], z0);
    z0 = fmaf(xv.w, p.We[96 + c], z0);
    zb = z0;
    ze_s[r][c] = z0;
    znt[r][c] = z0;
  }
  __syncthreads();

  // ---- pack-store buf0 + decode t=0 ----
  if (tid < 256) {
    const int rp = tid >> 5, cc = tid & 31, rr = rp * 2;
    const unsigned lo = (unsigned short)f2bs(znt[rr][cc]);
    const unsigned hi = (unsigned short)f2bs(znt[rr + 1][cc]);
    unsigned* dst = (unsigned*)p.ztr + (zt_idx(r0 + rr, cc) >> 1);
    __hip_atomic_store(dst, lo | (hi << 16), __ATOMIC_RELAXED, __HIP_MEMORY_SCOPE_AGENT);
  }
  if (tid < 16) {
    float acc = dsm[32];
#pragma unroll
    for (int jj = 0; jj < 16; ++jj) {
      float hv = dsm[jj];
#pragma unroll
      for (int hh = 0; hh < 32; ++hh) hv = fmaf(znt[tid][hh], Wd1_s[hh][jj], hv);
      acc = fmaf(fmaxf(hv, 0.f), dsm[16 + jj], acc);
    }
    p.out[r0 + tid] = 1.f / (1.f + expf(-acc));
  }
  gbar2(p, 0, bid, tid);

  // ---- 60 RK4 substeps ----
#pragma unroll 1
  for (int s = 0; s < 60; ++s) {
    const int t = s >> 2;
    const int j = (s & 3) + 1;
    const short* zi = p.ztr + (long)s * ZLEN;
    short* zo = p.ztr + (long)(s + 1) * ZLEN;
    const float* dxp = (j == 1) ? (p.dx0 + t * NI)
                     : (j == 4) ? (p.dx1 + t * NI) : (p.dxh + t * NI);

    // MFMA: zn(own 16 rows) = adj @ z; adj from L2, zT fresh from L3/L2
    f32x4 a0 = {0.f, 0.f, 0.f, 0.f}, a1 = {0.f, 0.f, 0.f, 0.f};
    const short* ap  = p.adjb + ((long)(bid * 128 + w * 8)) * 512 + lane8;
    const short* b0p = zi + ((long)(w * 8)) * 512 + lane8;
    const short* b1p = zi + ((long)(128 + w * 8)) * 512 + lane8;
#pragma unroll
    for (int i = 0; i < 8; ++i) {
      const short8 av = *(const short8*)(ap + i * 512);
      const short8 b0 = *(const short8*)(b0p + i * 512);
      const short8 b1 = *(const short8*)(b1p + i * 512);
      a0 = __builtin_amdgcn_mfma_f32_16x16x32_bf16(av, b0, a0, 0, 0, 0);
      a1 = __builtin_amdgcn_mfma_f32_16x16x32_bf16(av, b1, a1, 0, 0, 0);
    }
    {
      const int crow = (lane >> 4) * 4;   // C/D: col=lane&15, row=quad*4+reg
      const int ccol = lane & 15;
#pragma unroll
      for (int q = 0; q < 4; ++q) {
        red2[crow + q][ccol][w] = a0[q];
        red2[crow + q][ccol + 16][w] = a1[q];
      }
    }
    __syncthreads();

    // cross-wave reduction
    if (tid < 512) {
      float zn = 0.f;
#pragma unroll
      for (int q = 0; q < 16; ++q) zn += red2[r][c][q];
      zn_s[r][c] = zn;
    }
    __syncthreads();

    // h = relu(zn@Wg + ze@Wt + bg + bt)
    if (tid < 512) {
      float hv = bgt_s[c];
#pragma unroll
      for (int kk = 0; kk < 32; ++kk)
        hv = fmaf(zn_s[r][kk], Wg_s[kk][c], fmaf(ze_s[r][kk], Wt_s[kk][c], hv));
      h_s[r][c] = fmaxf(hv, 0.f);
    }
    __syncthreads();

    // sens/einsum + RK4 state update (state in registers)
    if (tid < 512) {
      const int row = r0 + r;
      float hr[32];
#pragma unroll
      for (int hp = 0; hp < 32; ++hp) hr[hp] = h_s[r][hp];
      float s0 = bp_s[c * 4], s1 = bp_s[c * 4 + 1];
      float s2 = bp_s[c * 4 + 2], s3 = bp_s[c * 4 + 3];
#pragma unroll
      for (int hp = 0; hp < 32; ++hp) {
        const float4 wv = *(const float4*)&Wp_s[hp][c * 4];
        s0 = fmaf(hr[hp], wv.x, s0);
        s1 = fmaf(hr[hp], wv.y, s1);
        s2 = fmaf(hr[hp], wv.z, s2);
        s3 = fmaf(hr[hp], wv.w, s3);
      }
      const float4 dxv = *(const float4*)&dxp[row * 4];
      const float kv = s0 * dxv.x + s1 * dxv.y + s2 * dxv.z + s3 * dxv.w;
      float znew;
      if (j == 4) {
        znew = zb + (k1r + 2.f * k2r + 2.f * k3r + kv) * (1.f / 6.f);
        zb = znew;
      } else {
        if (j == 1) k1r = kv; else if (j == 2) k2r = kv; else k3r = kv;
        znew = zb + ((j == 3) ? 1.f : 0.5f) * kv;
      }
      ze_s[r][c] = znew;
      znt[r][c] = znew;
    }
    __syncthreads();

    // pack-store buf[s+1] (agent-scope atomic u32 -> acked at L3)
    if (tid < 256) {
      const int rp = tid >> 5, cc = tid & 31, rr = rp * 2;
      const unsigned lo = (unsigned short)f2bs(znt[rr][cc]);
      const unsigned hi = (unsigned short)f2bs(znt[rr + 1][cc]);
      unsigned* dst = (unsigned*)zo + (zt_idx(r0 + rr, cc) >> 1);
      __hip_atomic_store(dst, lo | (hi << 16), __ATOMIC_RELAXED, __HIP_MEMORY_SCOPE_AGENT);
    }

    // fused decode of z_{t+1}
    if (j == 4 && tid < 16) {
      float acc = dsm[32];
#pragma unroll
      for (int jj = 0; jj < 16; ++jj) {
        float hv = dsm[jj];
#pragma unroll
        for (int hh = 0; hh < 32; ++hh) hv = fmaf(znt[tid][hh], Wd1_s[hh][jj], hv);
        acc = fmaf(fmaxf(hv, 0.f), dsm[16 + jj], acc);
      }
      p.out[(t + 1) * NN + r0 + tid] = 1.f / (1.f + expf(-acc));
    }

    if (s < 59) gbar2(p, s + 1, bid, tid);
  }
}

extern "C" void kernel_launch(void* const* d_in, const int* in_sizes, int n_in,
                              void* d_out, int out_size, void* d_ws, size_t ws_size,
                              hipStream_t stream) {
  (void)in_sizes; (void)n_in; (void)out_size; (void)ws_size;
  const float* x      = (const float*)d_in[0];
  const float* adj    = (const float*)d_in[1];
  const float* W_enc  = (const float*)d_in[2];
  const float* b_enc  = (const float*)d_in[3];
  const float* W_gcn  = (const float*)d_in[4];
  const float* b_gcn  = (const float*)d_in[5];
  const float* W_time = (const float*)d_in[6];
  const float* b_time = (const float*)d_in[7];
  const float* W_proj = (const float*)d_in[8];
  const float* b_proj = (const float*)d_in[9];
  const float* W_d1   = (const float*)d_in[10];
  const float* b_d1   = (const float*)d_in[11];
  const float* W_d2   = (const float*)d_in[12];
  const float* b_d2   = (const float*)d_in[13];

  // ws: bar 64 KB | dx 3x983 KB | zT ring 61x256 KB | adjb 32 MB  (~51 MB)
  unsigned* bar = (unsigned*)d_ws;          // 16384 u32
  float* dx0 = (float*)(bar + 16384);
  float* dxh = dx0 + 15 * NI;
  float* dx1 = dxh + 15 * NI;
  short* ztr = (short*)(dx1 + 15 * NI);
  short* adjb = ztr + 61L * ZLEN;

  k_cvt<<<256, 512, 0, stream>>>(adj, adjb);
  k_spline<<<64, 256, 0, stream>>>(x, dx0, dxh, dx1, bar);

  OdeP p;
  p.x = x; p.We = W_enc; p.be = b_enc; p.adjb = adjb;
  p.Wg = W_gcn; p.bg = b_gcn; p.Wt = W_time; p.bt = b_time;
  p.Wp = W_proj; p.bp = b_proj; p.Wd1 = W_d1; p.bd1 = b_d1;
  p.Wd2 = W_d2; p.bd2 = b_d2;
  p.dx0 = dx0; p.dxh = dxh; p.dx1 = dx1;
  p.ztr = ztr; p.bar = bar; p.out = (float*)d_out;

  void* args[] = { &p };
  hipError_t rc = hipLaunchCooperativeKernel((const void*)k_ode, dim3(256), dim3(1024),
                                             args, 0, stream);
  if (rc != hipSuccess) {
    // 256 blocks x 1024 threads, 1 block/CU -> co-resident in practice
    k_ode<<<256, 1024, 0, stream>>>(p);
  }
}